// Round 5
// baseline (1032.148 us; speedup 1.0000x reference)
//
#include <hip/hip_runtime.h>
#include <math.h>

// PNA-EGNN forward, MI355X, round 5: R4 kernels unchanged; workspace overlap fixed.
// R3/R4 bug: aggp (12800*1024 USHORTS = 6,553,600 float-slots) overlapped efph/efpl
// (aggp was sized as if ushort-count == float-count). Nodes >= 6400 clobbered edge
// planes -> absmax ~33 regardless of precision. Layout now disjoint.
// Fixed topology: bond deg=4 contiguous, comp deg=16 contiguous, 100 nodes/graph.
// hproj [12800][512] = [hWa | hWb+pre_b | hA | hB+pc_b1] (biases folded in).
// agg plane bf16-hi ushort [12800][1024]: [aggB(512) | aggC(512)].

#define N_NODES 12800
#define GRAPHS 128

typedef __attribute__((ext_vector_type(8))) short short8;
typedef __attribute__((ext_vector_type(4))) float f32x4;
#define MFMA16(a, b, c) __builtin_amdgcn_mfma_f32_16x16x32_bf16(a, b, c, 0, 0, 0)

static __device__ __forceinline__ float relu_f(float v) { return v > 0.0f ? v : 0.0f; }

static __device__ __forceinline__ unsigned short bf16rn(float x) {
  union { float f; unsigned u; } a; a.f = x;
  return (unsigned short)((a.u + 0x7fffu + ((a.u >> 16) & 1u)) >> 16);
}
static __device__ __forceinline__ float bf16tof(unsigned short h) {
  union { unsigned u; float f; } a; a.u = ((unsigned)h) << 16;
  return a.f;
}
static __device__ __forceinline__ void cvt_hl(float x, unsigned short& h, unsigned short& l) {
  h = bf16rn(x);
  l = bf16rn(x - bf16tof(h));
}

// ---------------- node input projection: Y = relu(X @ W + b), fp32 out ----------
__global__ __launch_bounds__(256) void in_proj_node(
    const float* __restrict__ X, const float* __restrict__ W,
    const float* __restrict__ bias, float* __restrict__ Y, int K) {
  int row = blockIdx.x * 2 + threadIdx.y;
  int c = threadIdx.x;
  float acc = bias[c];
  const float* xr = X + (size_t)row * K;
  for (int k = 0; k < K; ++k) acc += xr[k] * W[k * 128 + c];
  Y[(size_t)row * 128 + c] = relu_f(acc);
}

// ---------------- edge input projection: efp = relu(ef @ W + b) -> bf16 hi/lo ----
__global__ __launch_bounds__(256) void in_proj_edge(
    const float* __restrict__ X, const float* __restrict__ W,
    const float* __restrict__ bias, unsigned short* __restrict__ Yh,
    unsigned short* __restrict__ Yl) {
  int row = blockIdx.x * 2 + threadIdx.y;
  int c = threadIdx.x;
  float acc = bias[c];
  const float* xr = X + (size_t)row * 16;
#pragma unroll
  for (int k = 0; k < 16; ++k) acc += xr[k] * W[k * 128 + c];
  acc = relu_f(acc);
  unsigned short h, l;
  cvt_hl(acc, h, l);
  Yh[(size_t)row * 128 + c] = h;
  Yl[(size_t)row * 128 + c] = l;
}

// ---------------- weight prep: fold scalers + transpose + hi/lo split (R2-verified) --
__global__ __launch_bounds__(256) void fold_kernel(
    const float* __restrict__ pre_W, const float* __restrict__ pc_W1,
    const float* __restrict__ pc_W2, const float* __restrict__ post_W,
    const float* __restrict__ outn_W1, const float* __restrict__ outn_W2,
    unsigned short* __restrict__ wb) {
  int idx = blockIdx.x * 256 + threadIdx.x;  // 1,261,568 total
  const float C1 = 1.6094379124341003f;   // log 5
  const float C2 = 2.8332133440562162f;   // log 17
  float val;
  size_t ohi, olo;
  if (idx < 1228800) {
    int l = idx / 245760;
    int r = idx % 245760;
    size_t lb = (size_t)l * 491520;
    if (r < 65536) {  // hprojT [n=512][k=128]
      int n = r >> 7, k = r & 127;
      if (n < 128) val = pre_W[(size_t)l * 49152 + k * 128 + n];
      else if (n < 256) val = pre_W[(size_t)l * 49152 + (128 + k) * 128 + (n - 128)];
      else if (n < 384) val = pc_W1[(size_t)l * 32768 + k * 128 + (n - 256)];
      else val = pc_W1[(size_t)l * 32768 + (128 + k) * 128 + (n - 384)];
      ohi = lb + r; olo = ohi + 65536;
    } else if (r < 81920) {  // WcT
      int r2 = r - 65536; int n = r2 >> 7, k = r2 & 127;
      val = pre_W[(size_t)l * 49152 + (256 + k) * 128 + n];
      ohi = lb + 131072 + r2; olo = ohi + 16384;
    } else if (r < 98304) {  // W2T
      int r2 = r - 81920; int n = r2 >> 7, k = r2 & 127;
      val = pc_W2[(size_t)l * 16384 + k * 128 + n];
      ohi = lb + 163840 + r2; olo = ohi + 16384;
    } else {  // WfoldT [n=128][kk=1152]
      int r2 = r - 98304;
      int n = r2 / 1152, kk = r2 % 1152;
      const float* Wl = post_W + (size_t)l * 409600;
      if (kk < 128) val = Wl[kk * 128 + n];
      else if (kk < 640) {
        int j = kk - 128;
        val = Wl[(128 + j) * 128 + n] + C1 * Wl[(640 + j) * 128 + n] +
              (1.0f / C1) * Wl[(1152 + j) * 128 + n];
      } else {
        int j = kk - 640;
        val = Wl[(1664 + j) * 128 + n] + C2 * Wl[(2176 + j) * 128 + n] +
              (1.0f / C2) * Wl[(2688 + j) * 128 + n];
      }
      ohi = lb + 196608 + r2; olo = ohi + 147456;
    }
  } else {
    int r = idx - 1228800;
    if (r < 16384) {
      int n = r >> 7, k = r & 127;
      val = outn_W1[k * 128 + n];
      ohi = 2457600 + r; olo = ohi + 16384;
    } else {
      int r2 = r - 16384; int n = r2 >> 7, k = r2 & 127;
      val = outn_W2[k * 128 + n];
      ohi = 2490368 + r2; olo = ohi + 16384;
    }
  }
  unsigned short h, l2;
  cvt_hl(val, h, l2);
  wb[ohi] = h;
  wb[olo] = l2;
}

// ---------------- bias512: [l][512] = [0 | pre_b | 0 | pc_b1] ------------------------
__global__ __launch_bounds__(256) void bias_fold(const float* __restrict__ pre_b,
                                                 const float* __restrict__ pc_b1,
                                                 float* __restrict__ bias512) {
  int idx = blockIdx.x * 256 + threadIdx.x;
  if (idx >= 2560) return;
  int l = idx >> 9, c = idx & 511;
  float v = 0.f;
  if (c >= 128 && c < 256) v = pre_b[l * 128 + c - 128];
  else if (c >= 384) v = pc_b1[l * 128 + c - 384];
  bias512[idx] = v;
}

// ---------------- register MFMA GEMM: Y[M,N] = X[M,128] @ WT^T + bias -----------------
// Barrier-free, LDS-free. A: fp32 rows, cvt hi/lo in-register (3-term product).
// B: WT planes [N][128] hi/lo, per-lane direct loads (wave-owns-cols).
template <int MI, bool RELU>
__global__ __launch_bounds__(256) void rgemm(
    const float* __restrict__ X, const unsigned short* __restrict__ Wth,
    const unsigned short* __restrict__ Wtl, const float* __restrict__ bias,
    float* __restrict__ Y, int ystride) {
  int tid = threadIdx.x;
  int wave = tid >> 6, lane = tid & 63, quad = lane >> 4, l15 = lane & 15;
  int row0 = blockIdx.x * (MI * 16);
  int colbase = blockIdx.y * 128 + wave * 32;
  f32x4 acc[MI][2];
#pragma unroll
  for (int mi = 0; mi < MI; ++mi)
#pragma unroll
    for (int ni = 0; ni < 2; ++ni) acc[mi][ni] = (f32x4){0.f, 0.f, 0.f, 0.f};
  for (int kb = 0; kb < 128; kb += 32) {
    short8 ah[MI], al[MI];
#pragma unroll
    for (int mi = 0; mi < MI; ++mi) {
      const float* px = &X[(size_t)(row0 + mi * 16 + l15) * 128 + kb + quad * 8];
      float4 x0 = *(const float4*)px;
      float4 x1 = *(const float4*)(px + 4);
      unsigned short h_, l_;
#define CV(i, xx) { cvt_hl(xx, h_, l_); ah[mi][i] = (short)h_; al[mi][i] = (short)l_; }
      CV(0, x0.x) CV(1, x0.y) CV(2, x0.z) CV(3, x0.w)
      CV(4, x1.x) CV(5, x1.y) CV(6, x1.z) CV(7, x1.w)
#undef CV
    }
#pragma unroll
    for (int ni = 0; ni < 2; ++ni) {
      size_t bo = (size_t)(colbase + ni * 16 + l15) * 128 + kb + quad * 8;
      short8 bh = *(const short8*)(Wth + bo);
      short8 bl = *(const short8*)(Wtl + bo);
#pragma unroll
      for (int mi = 0; mi < MI; ++mi) {
        acc[mi][ni] = MFMA16(ah[mi], bh, acc[mi][ni]);
        acc[mi][ni] = MFMA16(ah[mi], bl, acc[mi][ni]);
        acc[mi][ni] = MFMA16(al[mi], bh, acc[mi][ni]);
      }
    }
  }
#pragma unroll
  for (int mi = 0; mi < MI; ++mi)
#pragma unroll
    for (int ni = 0; ni < 2; ++ni) {
      int col = colbase + ni * 16 + l15;
      float bj = bias[col];
#pragma unroll
      for (int r = 0; r < 4; ++r) {
        int row = row0 + mi * 16 + quad * 4 + r;
        float v = acc[mi][ni][r] + bj;
        if (RELU) v = relu_f(v);
        Y[(size_t)row * ystride + col] = v;
      }
    }
}

// ---------------- post GEMM: h_new = [h fp32 | agg bf16] @ WfT^T + b + h (resid) ------
__global__ __launch_bounds__(256) void post_rgemm(
    const float* __restrict__ X, const unsigned short* __restrict__ aggp,
    const unsigned short* __restrict__ Wth, const unsigned short* __restrict__ Wtl,
    const float* __restrict__ bias, float* __restrict__ Y) {
  int tid = threadIdx.x;
  int wave = tid >> 6, lane = tid & 63, quad = lane >> 4, l15 = lane & 15;
  int row0 = blockIdx.x * 32;
  int colbase = wave * 32;
  f32x4 acc[2][2];
#pragma unroll
  for (int mi = 0; mi < 2; ++mi)
#pragma unroll
    for (int ni = 0; ni < 2; ++ni) acc[mi][ni] = (f32x4){0.f, 0.f, 0.f, 0.f};
  for (int kb = 0; kb < 1152; kb += 32) {
    short8 ah[2], al[2];
    bool f32part = kb < 128;
    if (f32part) {
#pragma unroll
      for (int mi = 0; mi < 2; ++mi) {
        const float* px = &X[(size_t)(row0 + mi * 16 + l15) * 128 + kb + quad * 8];
        float4 x0 = *(const float4*)px;
        float4 x1 = *(const float4*)(px + 4);
        unsigned short h_, l_;
#define CV(i, xx) { cvt_hl(xx, h_, l_); ah[mi][i] = (short)h_; al[mi][i] = (short)l_; }
        CV(0, x0.x) CV(1, x0.y) CV(2, x0.z) CV(3, x0.w)
        CV(4, x1.x) CV(5, x1.y) CV(6, x1.z) CV(7, x1.w)
#undef CV
      }
    } else {
#pragma unroll
      for (int mi = 0; mi < 2; ++mi)
        ah[mi] = *(const short8*)&aggp[(size_t)(row0 + mi * 16 + l15) * 1024 +
                                       (kb - 128) + quad * 8];
    }
#pragma unroll
    for (int ni = 0; ni < 2; ++ni) {
      size_t bo = (size_t)(colbase + ni * 16 + l15) * 1152 + kb + quad * 8;
      short8 bh = *(const short8*)(Wth + bo);
      short8 bl = *(const short8*)(Wtl + bo);
#pragma unroll
      for (int mi = 0; mi < 2; ++mi) {
        acc[mi][ni] = MFMA16(ah[mi], bh, acc[mi][ni]);
        acc[mi][ni] = MFMA16(ah[mi], bl, acc[mi][ni]);
        if (f32part) acc[mi][ni] = MFMA16(al[mi], bh, acc[mi][ni]);
      }
    }
  }
#pragma unroll
  for (int mi = 0; mi < 2; ++mi)
#pragma unroll
    for (int ni = 0; ni < 2; ++ni) {
      int col = colbase + ni * 16 + l15;
      float bj = bias[col];
#pragma unroll
      for (int r = 0; r < 4; ++r) {
        int row = row0 + mi * 16 + quad * 4 + r;
        float v = acc[mi][ni][r] + bj + X[(size_t)row * 128 + col];
        Y[(size_t)row * 128 + col] = v;
      }
    }
}

// ---------------- fused bond (blocks 0..799) + comp (blocks 800..3999) ----------------
__global__ __launch_bounds__(256) void bondcomp(
    const unsigned short* __restrict__ efph, const unsigned short* __restrict__ efpl,
    const float* __restrict__ hproj, const unsigned short* __restrict__ wbL,
    const int* __restrict__ bond_src, const int* __restrict__ comp_src,
    const float* __restrict__ seW, const float* __restrict__ seb,
    const float* __restrict__ b2, unsigned short* __restrict__ aggp) {
  __shared__ __align__(16) short Ts_h[64][48];
  __shared__ __align__(16) short Ts_l[64][48];
  __shared__ float gpbuf[4][64];
  __shared__ float gateS[64];
  int tid = threadIdx.x;
  int wave = tid >> 6, lane = tid & 63, quad = lane >> 4, l15 = lane & 15;
  if (blockIdx.x < 800) {
    // ---- BOND: e = efp@Wc + (hWb+pre_b)[dst] + hWa[src]; PNA over deg=4 ----
    int e0 = blockIdx.x * 64;
    const unsigned short* Bh = wbL + 131072;
    const unsigned short* Bl = wbL + 147456;
    f32x4 acc[4][2];
#pragma unroll
    for (int mi = 0; mi < 4; ++mi)
#pragma unroll
      for (int ni = 0; ni < 2; ++ni) acc[mi][ni] = (f32x4){0.f, 0.f, 0.f, 0.f};
    for (int kb = 0; kb < 128; kb += 32) {
      short8 ah[4], al[4];
#pragma unroll
      for (int mi = 0; mi < 4; ++mi) {
        size_t ao = (size_t)(e0 + mi * 16 + l15) * 128 + kb + quad * 8;
        ah[mi] = *(const short8*)(efph + ao);
        al[mi] = *(const short8*)(efpl + ao);
      }
#pragma unroll
      for (int ni = 0; ni < 2; ++ni) {
        size_t bo = (size_t)(wave * 32 + ni * 16 + l15) * 128 + kb + quad * 8;
        short8 bh = *(const short8*)(Bh + bo);
        short8 bl = *(const short8*)(Bl + bo);
#pragma unroll
        for (int mi = 0; mi < 4; ++mi) {
          acc[mi][ni] = MFMA16(ah[mi], bh, acc[mi][ni]);
          acc[mi][ni] = MFMA16(ah[mi], bl, acc[mi][ni]);
          acc[mi][ni] = MFMA16(al[mi], bh, acc[mi][ni]);
        }
      }
    }
    int nodebase = e0 >> 2;
#pragma unroll
    for (int mi = 0; mi < 4; ++mi) {
      int ebase = e0 + mi * 16 + quad * 4;
      int node = nodebase + mi * 4 + quad;
      int s0 = bond_src[ebase], s1 = bond_src[ebase + 1];
      int s2 = bond_src[ebase + 2], s3 = bond_src[ebase + 3];
#pragma unroll
      for (int ni = 0; ni < 2; ++ni) {
        int col = wave * 32 + ni * 16 + l15;
        float basev = hproj[(size_t)node * 512 + 128 + col];  // hWb + pre_b
        float v0 = acc[mi][ni][0] + basev + hproj[(size_t)s0 * 512 + col];
        float v1 = acc[mi][ni][1] + basev + hproj[(size_t)s1 * 512 + col];
        float v2 = acc[mi][ni][2] + basev + hproj[(size_t)s2 * 512 + col];
        float v3 = acc[mi][ni][3] + basev + hproj[(size_t)s3 * 512 + col];
        float s = v0 + v1 + v2 + v3;
        float sq = v0 * v0 + v1 * v1 + v2 * v2 + v3 * v3;
        float mx = fmaxf(fmaxf(v0, v1), fmaxf(v2, v3));
        float mn = fminf(fminf(v0, v1), fminf(v2, v3));
        float mean = s * 0.25f;
        float var = relu_f(sq * 0.25f - mean * mean);
        size_t base = (size_t)node * 1024 + col;
        aggp[base] = bf16rn(mean);
        aggp[base + 128] = bf16rn(mx);
        aggp[base + 256] = bf16rn(mn);
        aggp[base + 384] = bf16rn(sqrtf(var + 1e-5f));
      }
    }
  } else {
    // ---- COMP: t = relu(hA[src] + (hB+pc_b1)[dst]) hi/lo; m = t@W2 + b2; gate; PNA(16)
    int e0 = (blockIdx.x - 800) * 64;
    const unsigned short* Bh = wbL + 163840;
    const unsigned short* Bl = wbL + 180224;
    int rr = tid >> 2, gg = tid & 3;
    int srcR = comp_src[e0 + rr];
    int nodeR = (e0 + rr) >> 4;
    const float* pa = hproj + (size_t)srcR * 512 + 256 + gg * 8;
    const float* pb = hproj + (size_t)nodeR * 512 + 384 + gg * 8;
    f32x4 acc[4][2];
#pragma unroll
    for (int mi = 0; mi < 4; ++mi)
#pragma unroll
      for (int ni = 0; ni < 2; ++ni) acc[mi][ni] = (f32x4){0.f, 0.f, 0.f, 0.f};
    for (int kb = 0; kb < 128; kb += 32) {
      if (kb) __syncthreads();
      {
        float4 a0 = *(const float4*)(pa + kb);
        float4 a1 = *(const float4*)(pa + kb + 4);
        float4 c0 = *(const float4*)(pb + kb);
        float4 c1 = *(const float4*)(pb + kb + 4);
        short8 vh, vl;
        unsigned short h_, l_;
#define CVT(i, xx) { cvt_hl(relu_f(xx), h_, l_); vh[i] = (short)h_; vl[i] = (short)l_; }
        CVT(0, a0.x + c0.x) CVT(1, a0.y + c0.y) CVT(2, a0.z + c0.z) CVT(3, a0.w + c0.w)
        CVT(4, a1.x + c1.x) CVT(5, a1.y + c1.y) CVT(6, a1.z + c1.z) CVT(7, a1.w + c1.w)
#undef CVT
        *(short8*)&Ts_h[rr][gg * 8] = vh;
        *(short8*)&Ts_l[rr][gg * 8] = vl;
      }
      __syncthreads();
      short8 ah[4], al[4];
#pragma unroll
      for (int mi = 0; mi < 4; ++mi) {
        ah[mi] = *(const short8*)&Ts_h[mi * 16 + l15][quad * 8];
        al[mi] = *(const short8*)&Ts_l[mi * 16 + l15][quad * 8];
      }
#pragma unroll
      for (int ni = 0; ni < 2; ++ni) {
        size_t bo = (size_t)(wave * 32 + ni * 16 + l15) * 128 + kb + quad * 8;
        short8 bh = *(const short8*)(Bh + bo);
        short8 bl = *(const short8*)(Bl + bo);
#pragma unroll
        for (int mi = 0; mi < 4; ++mi) {
          acc[mi][ni] = MFMA16(ah[mi], bh, acc[mi][ni]);
          acc[mi][ni] = MFMA16(ah[mi], bl, acc[mi][ni]);
          acc[mi][ni] = MFMA16(al[mi], bh, acc[mi][ni]);
        }
      }
    }
    // gate = sigmoid(sum_cols m*seW + seb)
    float sw0 = seW[wave * 32 + l15], sw1 = seW[wave * 32 + 16 + l15];
    float bb0 = b2[wave * 32 + l15], bb1 = b2[wave * 32 + 16 + l15];
#pragma unroll
    for (int mi = 0; mi < 4; ++mi) {
#pragma unroll
      for (int r = 0; r < 4; ++r) {
        float p = (acc[mi][0][r] + bb0) * sw0 + (acc[mi][1][r] + bb1) * sw1;
        p += __shfl_xor(p, 1, 64);
        p += __shfl_xor(p, 2, 64);
        p += __shfl_xor(p, 4, 64);
        p += __shfl_xor(p, 8, 64);
        if (l15 == 0) gpbuf[wave][mi * 16 + quad * 4 + r] = p;
      }
    }
    __syncthreads();
    if (tid < 64) {
      float g = gpbuf[0][tid] + gpbuf[1][tid] + gpbuf[2][tid] + gpbuf[3][tid] + seb[0];
      gateS[tid] = 1.f / (1.f + expf(-g));
    }
    __syncthreads();
    int nodebase = e0 >> 4;
#pragma unroll
    for (int mi = 0; mi < 4; ++mi) {
      int node = nodebase + mi;
#pragma unroll
      for (int ni = 0; ni < 2; ++ni) {
        float bb = ni ? bb1 : bb0;
        float s = 0.f, sq = 0.f, mx = -1e30f, mn = 1e30f;
#pragma unroll
        for (int r = 0; r < 4; ++r) {
          float v = (acc[mi][ni][r] + bb) * gateS[mi * 16 + quad * 4 + r];
          s += v; sq += v * v; mx = fmaxf(mx, v); mn = fminf(mn, v);
        }
        s += __shfl_xor(s, 16, 64); sq += __shfl_xor(sq, 16, 64);
        mx = fmaxf(mx, __shfl_xor(mx, 16, 64)); mn = fminf(mn, __shfl_xor(mn, 16, 64));
        s += __shfl_xor(s, 32, 64); sq += __shfl_xor(sq, 32, 64);
        mx = fmaxf(mx, __shfl_xor(mx, 32, 64)); mn = fminf(mn, __shfl_xor(mn, 32, 64));
        if (quad == 0) {
          int col = wave * 32 + ni * 16 + l15;
          float mean = s * 0.0625f;
          float var = relu_f(sq * 0.0625f - mean * mean);
          size_t base = (size_t)node * 1024 + 512 + col;
          aggp[base] = bf16rn(mean);
          aggp[base + 128] = bf16rn(mx);
          aggp[base + 256] = bf16rn(mn);
          aggp[base + 384] = bf16rn(sqrtf(var + 1e-5f));
        }
      }
    }
  }
}

// ---------------- tiny readout-path kernels (R1-verified) -----------------------------
template <bool RELU, bool RESID>
__global__ __launch_bounds__(256) void gemm_rrr(
    const float* __restrict__ X, int xstride, const float* __restrict__ W,
    const float* __restrict__ bias, const float* __restrict__ resid, int rstride,
    float* __restrict__ Y, int ystride, int Ktot) {
  __shared__ __align__(16) float Xs[32][68];
  __shared__ __align__(16) float Ws[64][128];
  int tid = threadIdx.x;
  int row0 = blockIdx.x * 32;
  int rg = tid >> 5;
  int c0 = (tid & 31) * 4;
  float acc[4][4] = {};
  for (int kb = 0; kb < Ktot; kb += 64) {
    __syncthreads();
    for (int i = tid; i < 32 * 64; i += 256) {
      int r = i >> 6, k = i & 63;
      Xs[r][k] = X[(size_t)(row0 + r) * xstride + kb + k];
    }
    for (int i = tid; i < 64 * 128; i += 256) {
      int k = i >> 7, c = i & 127;
      Ws[k][c] = W[(size_t)(kb + k) * 128 + c];
    }
    __syncthreads();
#pragma unroll
    for (int k4 = 0; k4 < 16; ++k4) {
      float4 w0 = *(const float4*)&Ws[k4 * 4 + 0][c0];
      float4 w1 = *(const float4*)&Ws[k4 * 4 + 1][c0];
      float4 w2 = *(const float4*)&Ws[k4 * 4 + 2][c0];
      float4 w3 = *(const float4*)&Ws[k4 * 4 + 3][c0];
#pragma unroll
      for (int r = 0; r < 4; ++r) {
        float4 x = *(const float4*)&Xs[rg * 4 + r][k4 * 4];
        acc[r][0] += x.x * w0.x + x.y * w1.x + x.z * w2.x + x.w * w3.x;
        acc[r][1] += x.x * w0.y + x.y * w1.y + x.z * w2.y + x.w * w3.y;
        acc[r][2] += x.x * w0.z + x.y * w1.z + x.z * w2.z + x.w * w3.z;
        acc[r][3] += x.x * w0.w + x.y * w1.w + x.z * w2.w + x.w * w3.w;
      }
    }
  }
  float bj[4] = {0.f, 0.f, 0.f, 0.f};
  if (bias) {
    bj[0] = bias[c0]; bj[1] = bias[c0 + 1]; bj[2] = bias[c0 + 2]; bj[3] = bias[c0 + 3];
  }
#pragma unroll
  for (int r = 0; r < 4; ++r) {
    int row = row0 + rg * 4 + r;
    float4 o;
    float* po = &o.x;
#pragma unroll
    for (int j = 0; j < 4; ++j) {
      float v = acc[r][j] + bj[j];
      if (RESID) v += resid[(size_t)row * rstride + c0 + j];
      if (RELU) v = relu_f(v);
      po[j] = v;
    }
    *(float4*)&Y[(size_t)row * ystride + c0] = o;
  }
}

__global__ __launch_bounds__(128) void readout_kernel(const float* __restrict__ nodeout,
                                                      float* __restrict__ r) {
  int g = blockIdx.x, c = threadIdx.x;
  float s = 0.f, mx = -1e30f;
  for (int i = 0; i < 100; ++i) {
    float v = nodeout[(size_t)(g * 100 + i) * 128 + c];
    s += v; mx = fmaxf(mx, v);
  }
  r[g * 384 + c] = s;
  r[g * 384 + 128 + c] = s * 0.01f;
  r[g * 384 + 256 + c] = mx;
}

__global__ __launch_bounds__(256) void final_kernel(const float* __restrict__ roh,
                                                    const float* __restrict__ W2,
                                                    const float* __restrict__ b2,
                                                    float* __restrict__ out) {
  int idx = blockIdx.x * 256 + threadIdx.x;  // 4096
  int g = idx >> 5, c = idx & 31;
  float acc = b2[c];
  for (int k = 0; k < 128; ++k) acc += roh[g * 128 + k] * W2[k * 32 + c];
  out[idx] = acc;
}

extern "C" void kernel_launch(void* const* d_in, const int* in_sizes, int n_in,
                              void* d_out, int out_size, void* d_ws, size_t ws_size,
                              hipStream_t stream) {
  const float* node_feat = (const float*)d_in[0];
  const float* edge_feat = (const float*)d_in[1];
  const int* bond_src = (const int*)d_in[2];
  const int* comp_src = (const int*)d_in[4];
  const float* in_W = (const float*)d_in[7];
  const float* in_b = (const float*)d_in[8];
  const float* ein_W = (const float*)d_in[9];
  const float* ein_b = (const float*)d_in[10];
  const float* pre_W = (const float*)d_in[11];
  const float* pre_b = (const float*)d_in[12];
  const float* pc_W1 = (const float*)d_in[13];
  const float* pc_b1 = (const float*)d_in[14];
  const float* pc_W2 = (const float*)d_in[15];
  const float* pc_b2 = (const float*)d_in[16];
  const float* se_W = (const float*)d_in[17];
  const float* se_b = (const float*)d_in[18];
  const float* post_W = (const float*)d_in[19];
  const float* post_b = (const float*)d_in[20];
  const float* outn_W1 = (const float*)d_in[21];
  const float* outn_b1 = (const float*)d_in[22];
  const float* outn_W2 = (const float*)d_in[23];
  const float* outn_b2 = (const float*)d_in[24];
  const float* ro_W1 = (const float*)d_in[25];
  const float* ro_b1 = (const float*)d_in[26];
  const float* ro_W2 = (const float*)d_in[27];
  const float* ro_b2 = (const float*)d_in[28];

  // ---- workspace layout (float-slot offsets; all spans disjoint) ----
  float* ws = (float*)d_ws;
  float* hbuf = ws;                                    // [0, 1,638,400)
  float* hnew = ws + 1638400;                          // [1,638,400, 3,276,800)
  float* hproj = ws + 3276800;                         // [3,276,800, 9,830,400)  12800x512 f32
  unsigned short* aggp = (unsigned short*)(ws + 9830400);
  //   12800*1024 ushort = 6,553,600 float-slots     -> [9,830,400, 16,384,000)
  unsigned short* efph = (unsigned short*)(ws + 16384000);
  unsigned short* efpl = efph + (size_t)51200 * 128;
  //   2*51200*128 ushort = 6,553,600 float-slots    -> [16,384,000, 22,937,600)
  unsigned short* wb = (unsigned short*)(ws + 22937600);
  //   2,523,136 ushort = 1,261,568 float-slots      -> [22,937,600, 24,199,168)
  float* bias512 = ws + 24199168;                      // [24,199,168, 24,201,728)
  float* tmp1 = ws + 24201728;                         // [24,201,728, 25,840,128)
  float* nodeout = ws + 25840128;                      // [25,840,128, 27,478,528)
  float* rbuf = ws + 27478528;                         // [27,478,528, 27,527,680)
  float* roh = ws + 27527680;                          // [27,527,680, 27,544,064) ~110 MB

  dim3 b2d(128, 2);
  in_proj_node<<<6400, b2d, 0, stream>>>(node_feat, in_W, in_b, hbuf, 64);
  in_proj_edge<<<25600, b2d, 0, stream>>>(edge_feat, ein_W, ein_b, efph, efpl);
  fold_kernel<<<4928, 256, 0, stream>>>(pre_W, pc_W1, pc_W2, post_W, outn_W1, outn_W2, wb);
  bias_fold<<<10, 256, 0, stream>>>(pre_b, pc_b1, bias512);

  float* cur = hbuf;
  float* nxt = hnew;
  for (int l = 0; l < 5; ++l) {
    size_t lb = (size_t)l * 491520;
    rgemm<2, false><<<dim3(400, 4), 256, 0, stream>>>(
        cur, wb + lb, wb + lb + 65536, bias512 + l * 512, hproj, 512);
    bondcomp<<<4000, 256, 0, stream>>>(efph, efpl, hproj, wb + lb, bond_src, comp_src,
                                       se_W + l * 128, se_b + l, pc_b2 + l * 128, aggp);
    post_rgemm<<<400, 256, 0, stream>>>(cur, aggp, wb + lb + 196608, wb + lb + 344064,
                                        post_b + l * 128, nxt);
    float* t = cur; cur = nxt; nxt = t;
  }
  rgemm<2, true><<<dim3(400, 1), 256, 0, stream>>>(
      cur, wb + 2457600, wb + 2473984, outn_b1, tmp1, 128);
  rgemm<2, false><<<dim3(400, 1), 256, 0, stream>>>(
      tmp1, wb + 2490368, wb + 2506752, outn_b2, nodeout, 128);
  readout_kernel<<<GRAPHS, 128, 0, stream>>>(nodeout, rbuf);
  gemm_rrr<true, false><<<4, 256, 0, stream>>>(rbuf, 384, ro_W1, ro_b1, nullptr, 0,
                                               roh, 128, 384);
  final_kernel<<<16, 256, 0, stream>>>(roh, ro_W2, ro_b2, (float*)d_out);
}